// Round 8
// baseline (138.806 us; speedup 1.0000x reference)
//
#include <hip/hip_runtime.h>
#include <hip/hip_bf16.h>

// ScaledDotProductAttention B=2,H=16,S=2048,D=64 causal, f32 in/out (probed).
// v18: v17 + counted-vmcnt schedule (T3/T4 minimum form). r7 post-mortem:
// wall = longest block (32 iters) x 3400 cyc/iter; __syncthreads = vmcnt(0)
// drain of the SAME-iter DMA -> prefetch never spanned the barrier (m97
// mechanism). Now: depth-2 prefetch, raw s_barrier, vmcnt(8) steady state
// (never 0 except tail), per m201 template:
//   prologue: stage(t0,b0); stage(t1,b1); vmcnt(8); barrier
//   iter kt:  ds_read(cb); lgkmcnt(0); B1; stage(kt+2 -> cb);
//             setprio(1) compute setprio(0); vmcnt(8 | 0 at tail); B2
// Race analysis: lgkm(0)+B1 orders all waves' reads-of-cb before overwrite;
// own vmcnt(8)+B2 orders DMA-writes before any wave reads nb next iter.
// Prep (swizzled ws), decode (quad-balance, 4bh/XCD), body (no-max exp2,
// sigma PV, CSC in Q), epilogue: verbatim v17 (passed, conflicts=0).

typedef __attribute__((ext_vector_type(8))) short  s8v;   // 8 x bf16
typedef __attribute__((ext_vector_type(4))) float  f4v;   // MFMA acc
typedef __attribute__((ext_vector_type(4))) unsigned int u4v;

#define SEQ 2048
#define DH  64
#define BHN 32
#define CSC 0.18033688f   // (1/sqrt(64)) * log2(e)

#if __has_builtin(__builtin_amdgcn_exp2f)
#define EXP2(x) __builtin_amdgcn_exp2f(x)
#else
#define EXP2(x) exp2f(x)
#endif

__device__ __forceinline__ unsigned short f2bf(float x) {
  union { float f; unsigned int u; } v; v.f = x;
  return (unsigned short)((v.u + 0x7fffu + ((v.u >> 16) & 1u)) >> 16);  // RNE
}
__device__ __forceinline__ float bf2f(unsigned short x) {
  union { unsigned int u; float f; } v; v.u = ((unsigned int)x) << 16;
  return v.f;
}
__device__ __forceinline__ int pack_bf2(float a, float b) {
  union { __hip_bfloat162 h; int i; } u;
  u.h = __float22bfloat162_rn(make_float2(a, b));   // a->low, b->high
  return u.i;
}
__device__ __forceinline__ bool probe_is_f32(const unsigned short* p) {
  const unsigned e = (p[threadIdx.x & 63] >> 7) & 0xFFu;
  return __ballot(e >= 0x89u) != 0ULL;
}
__device__ __forceinline__ s8v cvt8(const float* p) {
  float4 a = *(const float4*)p;
  float4 b = *(const float4*)(p + 4);
  s8v r;
  r[0] = (short)f2bf(a.x); r[1] = (short)f2bf(a.y);
  r[2] = (short)f2bf(a.z); r[3] = (short)f2bf(a.w);
  r[4] = (short)f2bf(b.x); r[5] = (short)f2bf(b.y);
  r[6] = (short)f2bf(b.z); r[7] = (short)f2bf(b.w);
  return r;
}
__device__ __forceinline__ s8v cvt8s(const float* p, float s) {
  float4 a = *(const float4*)p;
  float4 b = *(const float4*)(p + 4);
  s8v r;
  r[0] = (short)f2bf(a.x * s); r[1] = (short)f2bf(a.y * s);
  r[2] = (short)f2bf(a.z * s); r[3] = (short)f2bf(a.w * s);
  r[4] = (short)f2bf(b.x * s); r[5] = (short)f2bf(b.y * s);
  r[6] = (short)f2bf(b.z * s); r[7] = (short)f2bf(b.w * s);
  return r;
}
__device__ __forceinline__ void gld16(const void* g, void* l) {
  __builtin_amdgcn_global_load_lds(
      (const __attribute__((address_space(1))) void*)g,
      (__attribute__((address_space(3))) void*)l, 16, 0, 0);
}

// ---- pre-pass: z=0 K->bf16 swizzled; z=1 V->Vt chunked + swizzled ----
// Both workspaces: row-major 64-short (128B) rows; within each row the 16B
// chunks are stored at physical col = logical_col ^ ((row&7)<<4).
// Vt logical chunk order (per 64-key tile, row d): chunk c=kc*4+quad holds
// keys {32kc+4quad+0..3, 32kc+16+4quad+0..3} (one 16B PV B-frag).
__global__ __launch_bounds__(256) void prep_kernel(
    const void* __restrict__ Kv, const void* __restrict__ Vv,
    unsigned short* __restrict__ Kbf, unsigned short* __restrict__ Vt) {
  const int bh = blockIdx.y;
  const int s0 = blockIdx.x * 64;
  const int t  = threadIdx.x;
  if (blockIdx.z == 0) {
    const unsigned short* K16 = (const unsigned short*)Kv;
    const float*          KF  = (const float*)Kv;
    const bool isF32 = probe_is_f32(K16);
    const int sr  = t >> 2;
    const int cb0 = (t & 3) * 32;                    // byte col of 1st chunk
    const int xs  = (sr & 7) << 4;
    const size_t src = ((size_t)(bh * SEQ + s0 + sr)) * DH + (t & 3) * 16;
    s8v a0, a1;
    if (!isF32) { a0 = *(const s8v*)(K16 + src); a1 = *(const s8v*)(K16 + src + 8); }
    else        { a0 = cvt8(KF + src);           a1 = cvt8(KF + src + 8); }
    char* rowp = (char*)Kbf + ((size_t)(bh * SEQ + s0 + sr)) * 128;
    *(s8v*)(rowp + (cb0 ^ xs))        = a0;
    *(s8v*)(rowp + ((cb0 + 16) ^ xs)) = a1;
  } else {
    __shared__ __align__(16) unsigned short T[64][72];
    const unsigned short* V16 = (const unsigned short*)Vv;
    const float*          VF  = (const float*)Vv;
    const bool isF32 = probe_is_f32(V16);
    {
      const int sr = t >> 2, c0 = (t & 3) * 16;
      const size_t base = ((size_t)(bh * SEQ + s0 + sr)) * DH + c0;
      s8v a0, a1;
      if (!isF32) { a0 = *(const s8v*)(V16 + base); a1 = *(const s8v*)(V16 + base + 8); }
      else        { a0 = cvt8(VF + base);           a1 = cvt8(VF + base + 8); }
      *(s8v*)&T[sr][c0]     = a0;
      *(s8v*)&T[sr][c0 + 8] = a1;
    }
    __syncthreads();
    {
      const int d  = t & 63;
      const int hs = t >> 6;            // 0..3 -> chunks 2hs, 2hs+1
      const int xs = (d & 7) << 4;
      char* rowp = (char*)Vt + (size_t)bh * SEQ * 128 + (size_t)s0 * 128
                 + (size_t)d * 128;
#pragma unroll
      for (int cc = 0; cc < 2; ++cc) {
        const int c  = hs * 2 + cc;
        const int kA = (c >> 2) * 32 + (c & 3) * 4;  // base key of chunk
        unsigned int wb[4];
        wb[0] = (unsigned int)T[kA + 0][d]  | ((unsigned int)T[kA + 1][d]  << 16);
        wb[1] = (unsigned int)T[kA + 2][d]  | ((unsigned int)T[kA + 3][d]  << 16);
        wb[2] = (unsigned int)T[kA + 16][d] | ((unsigned int)T[kA + 17][d] << 16);
        wb[3] = (unsigned int)T[kA + 18][d] | ((unsigned int)T[kA + 19][d] << 16);
        u4v q = { wb[0], wb[1], wb[2], wb[3] };
        *(u4v*)(rowp + ((c * 16) ^ xs)) = q;
      }
    }
  }
}

// ---- main: flash attention, 64 q-rows/block (2 waves x 32q), DMA-staged
// double-buffered LDS, counted-vmcnt pipeline (depth 2) ----
__global__ __launch_bounds__(128, 2) void attn_kernel(
    const void* __restrict__ Qv, const unsigned short* __restrict__ Kbf,
    const unsigned short* __restrict__ Vt, void* __restrict__ Outv) {
  __shared__ __align__(16) char Lds[2][16384];   // [buf][K 8KB | V 8KB], linear

  const unsigned short* Q16 = (const unsigned short*)Qv;
  const float*          QF  = (const float*)Qv;
  const bool isF32 = probe_is_f32(Q16);

  // decode: xcd=blk&7 (4 bh per XCD L2); qb quad {7-a,8+a,23-a,24+a} sums 66/CU
  const int blk = blockIdx.x;
  const int bh  = (blk & 7) * 4 + ((blk >> 3) & 3);
  const int a   = (blk >> 5) & 7;
  const int bsl = blk >> 8;                            // 0..3
  const int qb  = (bsl == 0) ? (7 - a) : (bsl == 1) ? (8 + a)
                : (bsl == 2) ? (23 - a) : (24 + a);

  const int tid  = threadIdx.x;
  const int w    = tid >> 6;                           // wave 0..1
  const int lane = tid & 63;
  const int quad = lane >> 4;
  const int c16  = lane & 15;
  const int q0   = qb * 64 + w * 32;                   // this wave's 32 q-rows

  const size_t bh_off = (size_t)bh * SEQ * DH;

  // Q fragments: 2 row-halves x 2 k-chunks, prescaled by CSC
  s8v aq[2][2];
#pragma unroll
  for (int h = 0; h < 2; ++h)
#pragma unroll
    for (int kc = 0; kc < 2; ++kc) {
      const size_t idx = bh_off + (size_t)(q0 + h * 16 + c16) * DH + kc * 32 + quad * 8;
      if (isF32) aq[h][kc] = cvt8s(QF + idx, CSC);
      else {
        s8v aa = *(const s8v*)(Q16 + idx);
#pragma unroll
        for (int t = 0; t < 8; ++t)
          aa[t] = (short)f2bf(bf2f((unsigned short)aa[t]) * CSC);
        aq[h][kc] = aa;
      }
    }

  f4v o[2][4];
  float l[2] = {0.f, 0.f};
#pragma unroll
  for (int h = 0; h < 2; ++h)
#pragma unroll
    for (int i = 0; i < 4; ++i) { f4v z = {0.f, 0.f, 0.f, 0.f}; o[h][i] = z; }

  const int ntiles = qb + 1;

  // frag read addressing (swizzled): row*128 + ((kc*64 + quad*16) ^ xorl)
  const int xorl = (c16 & 7) << 4;
  const int fc0  = (quad * 16) ^ xorl;
  const int fc1  = (64 + quad * 16) ^ xorl;
  const int frow = c16 * 128;

  // DMA sources: per-lane 16B of the 8KB tile (tile stride 4096 shorts)
  const unsigned short* Kg = Kbf + bh_off + (size_t)lane * 8;
  const unsigned short* Vg = Vt  + bh_off + (size_t)lane * 8;

  auto stage = [&](int tile, int buf) {   // 8 gld16 per wave
    if (w == 0) {
      const unsigned short* g = Kg + (size_t)tile * 4096;
      char* lp = &Lds[buf][0];
#pragma unroll
      for (int j = 0; j < 8; ++j) gld16(g + j * 512, lp + j * 1024);
    } else {
      const unsigned short* g = Vg + (size_t)tile * 4096;
      char* lp = &Lds[buf][8192];
#pragma unroll
      for (int j = 0; j < 8; ++j) gld16(g + j * 512, lp + j * 1024);
    }
  };

  // prologue: tiles 0,1 in flight; wait tile 0 only (tile 1 keeps flying)
  stage(0, 0);
  if (1 < ntiles) {
    stage(1, 1);
    asm volatile("s_waitcnt vmcnt(8)" ::: "memory");
  } else {
    asm volatile("s_waitcnt vmcnt(0)" ::: "memory");
  }
  __builtin_amdgcn_sched_barrier(0);
  __builtin_amdgcn_s_barrier();

  for (int kt = 0; kt < ntiles; ++kt) {
    const int cb = kt & 1;

    // frag reads from current buffer (compiler-tracked lgkm waits)
    const char* Kl = &Lds[cb][0];
    const char* Vl = &Lds[cb][8192];
    s8v kb[4][2], vb[4][2];
#pragma unroll
    for (int nt = 0; nt < 4; ++nt) {
      kb[nt][0] = *(const s8v*)(Kl + frow + nt * 2048 + fc0);
      kb[nt][1] = *(const s8v*)(Kl + frow + nt * 2048 + fc1);
      vb[nt][0] = *(const s8v*)(Vl + frow + nt * 2048 + fc0);
      vb[nt][1] = *(const s8v*)(Vl + frow + nt * 2048 + fc1);
    }
    asm volatile("s_waitcnt lgkmcnt(0)" ::: "memory");   // reads of cb complete
    __builtin_amdgcn_sched_barrier(0);
    __builtin_amdgcn_s_barrier();                        // B1: cb is free

    const bool st2 = (kt + 2 < ntiles);
    if (st2) stage(kt + 2, cb);                          // overwrite freed buf

    __builtin_amdgcn_s_setprio(1);
    // S^T = K.Q^T: lane holds query=c16 (per half h), keys=nt*16+quad*4+r
    float p[2][4][4];
#pragma unroll
    for (int h = 0; h < 2; ++h)
#pragma unroll
      for (int nt = 0; nt < 4; ++nt) {
        f4v acc = {0.f, 0.f, 0.f, 0.f};
        acc = __builtin_amdgcn_mfma_f32_16x16x32_bf16(kb[nt][0], aq[h][0], acc, 0, 0, 0);
        acc = __builtin_amdgcn_mfma_f32_16x16x32_bf16(kb[nt][1], aq[h][1], acc, 0, 0, 0);
#pragma unroll
        for (int r = 0; r < 4; ++r) p[h][nt][r] = EXP2(acc[r]);  // no-max: f32-safe
      }
    if (kt * 64 + 63 > q0) {  // diagonal tile: zero masked probs
#pragma unroll
      for (int h = 0; h < 2; ++h) {
        const int qmk = q0 + h * 16 + c16 - kt * 64 - quad * 4;
#pragma unroll
        for (int nt = 0; nt < 4; ++nt)
#pragma unroll
          for (int r = 0; r < 4; ++r)
            if (nt * 16 + r > qmk) p[h][nt][r] = 0.f;
      }
    }
#pragma unroll
    for (int h = 0; h < 2; ++h) {
      float s = 0.f;
#pragma unroll
      for (int nt = 0; nt < 4; ++nt)
        s += (p[h][nt][0] + p[h][nt][1]) + (p[h][nt][2] + p[h][nt][3]);
      l[h] += s;
      // P A-frags: pure in-lane pack (sigma ordering); PV with shared sigma
#pragma unroll
      for (int kc = 0; kc < 2; ++kc) {
        union { int d[4]; s8v v; } u;
        u.d[0] = pack_bf2(p[h][2 * kc][0],     p[h][2 * kc][1]);
        u.d[1] = pack_bf2(p[h][2 * kc][2],     p[h][2 * kc][3]);
        u.d[2] = pack_bf2(p[h][2 * kc + 1][0], p[h][2 * kc + 1][1]);
        u.d[3] = pack_bf2(p[h][2 * kc + 1][2], p[h][2 * kc + 1][3]);
#pragma unroll
        for (int dt = 0; dt < 4; ++dt)
          o[h][dt] = __builtin_amdgcn_mfma_f32_16x16x32_bf16(u.v, vb[dt][kc], o[h][dt], 0, 0, 0);
      }
    }
    __builtin_amdgcn_s_setprio(0);

    // wait next tile's DMA: kt+1's 8 loads complete; kt+2's 8 keep flying
    if (st2) asm volatile("s_waitcnt vmcnt(8)" ::: "memory");
    else     asm volatile("s_waitcnt vmcnt(0)" ::: "memory");
    __builtin_amdgcn_sched_barrier(0);
    __builtin_amdgcn_s_barrier();                        // B2: nb resident for all
  }

  // ---- epilogue: wave-local, per row-half ----
#pragma unroll
  for (int h = 0; h < 2; ++h) {
    float lv = l[h];
    lv += __shfl_xor(lv, 16);
    lv += __shfl_xor(lv, 32);     // l(query=c16), replicated over quads
    union { float f; int i; } lu; lu.f = lv;
    float invr[4];
#pragma unroll
    for (int rr = 0; rr < 4; ++rr) {
      union { int i; float f; } tf;
      tf.i = __builtin_amdgcn_ds_bpermute(4 * (quad * 4 + rr), lu.i);
      invr[rr] = 1.0f / tf.f;     // l for my output row quad*4+rr
    }
    if (isF32) {
      float* OF = (float*)Outv;
#pragma unroll
      for (int rr = 0; rr < 4; ++rr) {
        const size_t rb = bh_off + (size_t)(q0 + h * 16 + quad * 4 + rr) * DH + c16;
#pragma unroll
        for (int dt = 0; dt < 4; ++dt)
          OF[rb + dt * 16] = o[h][dt][rr] * invr[rr];
      }
    } else {
      unsigned short* O16 = (unsigned short*)Outv;
#pragma unroll
      for (int rr = 0; rr < 4; ++rr) {
        const size_t rb = bh_off + (size_t)(q0 + h * 16 + quad * 4 + rr) * DH + c16;
#pragma unroll
        for (int dt = 0; dt < 4; ++dt)
          O16[rb + dt * 16] = f2bf(o[h][dt][rr] * invr[rr]);
      }
    }
  }
}

extern "C" void kernel_launch(void* const* d_in, const int* in_sizes, int n_in,
                              void* d_out, int out_size, void* d_ws, size_t ws_size,
                              hipStream_t stream) {
  const void* Q = d_in[0];
  const void* K = d_in[1];
  const void* V = d_in[2];
  unsigned short* Kbf = (unsigned short*)d_ws;                     // 8.39 MB
  unsigned short* Vt  = Kbf + (size_t)BHN * SEQ * DH;              // 8.39 MB

  dim3 g1(SEQ / 64, BHN, 2);
  prep_kernel<<<g1, 256, 0, stream>>>(K, V, Kbf, Vt);
  attn_kernel<<<dim3(1024), 128, 0, stream>>>(Q, Kbf, Vt, d_out);
}